// Round 1
// baseline (879.850 us; speedup 1.0000x reference)
//
#include <hip/hip_runtime.h>
#include <stdint.h>

// ============================================================================
// WindowCrossAttention on MI355X (gfx950) — v2: 2 blocks/CU.
//   B=4096 windows, N=64 tokens, C=128, H=4 heads, HD=32, NW=1024 mask groups.
//   One block (512 thr = 8 waves) per window; fully fused.
//   Key change vs v1: LDS 152 KiB -> 76 KiB so 2 blocks co-reside per CU:
//     * swapped QK^T (S^T = K x Q) -> softmax + P->A-frag repack fully in
//       registers (shfl quad-exchange), sP eliminated.
//     * V held in registers through phase A, written into the DEAD K region
//       of the opposite side (after its kf reads) as V^T.
//     * O aliases the dead Q region (stride 136).
//   bf16 MFMA 16x16x32 (A: m=lane&15,k=quad*8+j; C: n=lane&15, m=quad*4+r).
//   VGPR must stay <=128 (4 waves/SIMD) -> __launch_bounds__(512, 4).
// ============================================================================

typedef __attribute__((ext_vector_type(8))) short short8;   // 8 bf16
typedef __attribute__((ext_vector_type(4))) short short4v;  // 4 bf16 (8B)
typedef __attribute__((ext_vector_type(4))) float f32x4;    // MFMA C/D frag
typedef __attribute__((ext_vector_type(2))) unsigned int uint2v;

#define MFMA(a, b, c) __builtin_amdgcn_mfma_f32_16x16x32_bf16((a), (b), (c), 0, 0, 0)

static __device__ __forceinline__ unsigned short f2bf(float f) {
  union { float f; uint32_t u; } v; v.f = f;
  uint32_t u = v.u + (0x7fffu + ((v.u >> 16) & 1u));  // RNE, no NaN in data
  return (unsigned short)(u >> 16);
}
static __device__ __forceinline__ uint32_t pk2(float a, float b) {
  return (uint32_t)f2bf(a) | ((uint32_t)f2bf(b) << 16);
}

// ---------------------------------------------------------------------------
// Prep: pack weights to bf16 fragment-major (B-operand of 16x16x32 tiles);
// gather bias tables into the S^T register layout:
//   biasL[h][ni][mt][lane][r] = tbl[rpi[i*64+j]][h],
//   i = ni*16 + (lane&15)  (query), j = mt*16 + (lane>>4)*4 + r  (key).
// ---------------------------------------------------------------------------
__global__ __launch_bounds__(256) void prep_kernel(
    const float* __restrict__ wqkv1, const float* __restrict__ wqkv2,
    const float* __restrict__ wproj1, const float* __restrict__ wproj2,
    const float* __restrict__ tbl1, const float* __restrict__ tbl2,
    const int* __restrict__ rpi,
    unsigned short* __restrict__ wq1p, unsigned short* __restrict__ wq2p,
    unsigned short* __restrict__ wp1p, unsigned short* __restrict__ wp2p,
    float* __restrict__ bias1, float* __restrict__ bias2) {
  int tid = blockIdx.x * 256 + threadIdx.x;
  if (tid < 12288) {  // wqkv1 / wqkv2: K=128 (kt 0..3), N=384 (nt 0..23)
    const float* W = (tid < 6144) ? wqkv1 : wqkv2;
    unsigned short* P = (tid < 6144) ? wq1p : wq2p;
    int local = (tid < 6144) ? tid : tid - 6144;
    int tile = local >> 6, lane = local & 63;
    int nt = tile >> 2, kt = tile & 3;
    int n = nt * 16 + (lane & 15);
    int kb = kt * 32 + (lane >> 4) * 8;
    unsigned short* dst = P + (size_t)(tile * 64 + lane) * 8;
#pragma unroll
    for (int j = 0; j < 8; ++j) dst[j] = f2bf(W[(kb + j) * 384 + n]);
  } else if (tid < 16384) {  // wproj1 / wproj2
    int local = tid - 12288;
    const float* W = (local < 2048) ? wproj1 : wproj2;
    unsigned short* P = (local < 2048) ? wp1p : wp2p;
    local &= 2047;
    int tile = local >> 6, lane = local & 63;
    int nt = tile >> 2, kt = tile & 3;
    int n = nt * 16 + (lane & 15);
    int kb = kt * 32 + (lane >> 4) * 8;
    unsigned short* dst = P + (size_t)(tile * 64 + lane) * 8;
#pragma unroll
    for (int j = 0; j < 8; ++j) dst[j] = f2bf(W[(kb + j) * 128 + n]);
  } else if (tid < 49152) {  // bias gather into register layout
    int local = tid - 16384;
    const float* T = (local < 16384) ? tbl1 : tbl2;
    float* D = (local < 16384) ? bias1 : bias2;
    local &= 16383;  // h(4) ni(4) mt(4) lane(64) r(4)
    int r = local & 3;
    int ln = (local >> 2) & 63;
    int mt = (local >> 8) & 3;
    int ni = (local >> 10) & 3;
    int h = local >> 12;
    int i = ni * 16 + (ln & 15);
    int j = mt * 16 + (ln >> 4) * 4 + r;
    D[local] = T[rpi[i * 64 + j] * 4 + h];
  }
}

// ---------------------------------------------------------------------------
// Main fused kernel. LDS (77824 B total -> 2 blocks/CU):
//   sQ[2][4][64][36] bf16 : Q per side/head (token, hd), stride 36
//                           -> later aliased per side as O [64][136].
//   sK[2][4][64][40] bf16 : K per side/head, stride 40
//                           -> later aliased per side as V^T [4][32][72].
// ---------------------------------------------------------------------------
__global__ __launch_bounds__(512, 4) void wca_kernel(
    const float* __restrict__ x, const float* __restrict__ y,
    const float* __restrict__ mask,
    const float* __restrict__ bqkv1, const float* __restrict__ bqkv2,
    const float* __restrict__ bproj1, const float* __restrict__ bproj2,
    const float* __restrict__ g1, const float* __restrict__ be1,
    const float* __restrict__ g2, const float* __restrict__ be2,
    const unsigned short* __restrict__ wq1p, const unsigned short* __restrict__ wq2p,
    const unsigned short* __restrict__ wp1p, const unsigned short* __restrict__ wp2p,
    const float* __restrict__ biasT1, const float* __restrict__ biasT2,
    float* __restrict__ out) {
  __shared__ __align__(16) unsigned short sQ[2][4][64][36];
  __shared__ __align__(16) unsigned short sK[2][4][64][40];

  const int b = blockIdx.x;
  const int tid = (int)threadIdx.x;
  const int wave = tid >> 6;
  const int lane = tid & 63;
  const int quad = lane >> 4;
  const int col = lane & 15;
  const int sideA = wave >> 2;  // phase-A identity
  const int ntg = wave & 3;

  uint32_t vpk[2][4][2];  // V tiles held in regs (bf16 packed): [vt][mt][pair]

  // ============================ Phase A: QKV GEMM ===========================
  // wave = (sideA, ntg); tiles nt = ntg + 4t: t0,1 -> Q; t2,3 -> K; V last.
  {
    const float* src = (sideA ? y : x) + (size_t)b * 8192;
    const unsigned short* wp = sideA ? wq2p : wq1p;
    const float* bq = sideA ? bqkv2 : bqkv1;

    short8 afrag[4][4];
#pragma unroll
    for (int mt = 0; mt < 4; ++mt) {
      int m = mt * 16 + col;
#pragma unroll
      for (int ks = 0; ks < 4; ++ks) {
        const float* p = src + m * 128 + ks * 32 + quad * 8;
        float4 lo = *(const float4*)(p);
        float4 hi4 = *(const float4*)(p + 4);
        short8 f;
        f[0] = (short)f2bf(lo.x); f[1] = (short)f2bf(lo.y);
        f[2] = (short)f2bf(lo.z); f[3] = (short)f2bf(lo.w);
        f[4] = (short)f2bf(hi4.x); f[5] = (short)f2bf(hi4.y);
        f[6] = (short)f2bf(hi4.z); f[7] = (short)f2bf(hi4.w);
        afrag[mt][ks] = f;
      }
    }

#pragma unroll 1
    for (int t = 0; t < 4; ++t) {  // Q then K tiles
      int nt = ntg + t * 4;
      float bias = bq[nt * 16 + col];
      short8 bfrag[4];
#pragma unroll
      for (int ks = 0; ks < 4; ++ks)
        bfrag[ks] = *(const short8*)(wp + (size_t)((nt * 4 + ks) * 64 + lane) * 8);
      int cw = (nt & 7) * 16 + col;
      int hq = cw >> 5, d = cw & 31;
#pragma unroll
      for (int mt = 0; mt < 4; ++mt) {
        f32x4 acc = {bias, bias, bias, bias};
#pragma unroll
        for (int ks = 0; ks < 4; ++ks) acc = MFMA(afrag[mt][ks], bfrag[ks], acc);
#pragma unroll
        for (int r = 0; r < 4; ++r) {
          int row = mt * 16 + quad * 4 + r;
          unsigned short v = f2bf(acc[r]);
          if (t < 2) sQ[sideA][hq][row][d] = v;
          else       sK[sideA][hq][row][d] = v;
        }
      }
    }

#pragma unroll
    for (int vt = 0; vt < 2; ++vt) {  // V tiles: keep in regs, bf16-packed
      int nt = ntg + 16 + vt * 4;
      float bias = bq[nt * 16 + col];
      short8 bfrag[4];
#pragma unroll
      for (int ks = 0; ks < 4; ++ks)
        bfrag[ks] = *(const short8*)(wp + (size_t)((nt * 4 + ks) * 64 + lane) * 8);
#pragma unroll
      for (int mt = 0; mt < 4; ++mt) {
        f32x4 acc = {bias, bias, bias, bias};
#pragma unroll
        for (int ks = 0; ks < 4; ++ks) acc = MFMA(afrag[mt][ks], bfrag[ks], acc);
        vpk[vt][mt][0] = pk2(acc[0], acc[1]);  // tokens quad*4+0,1
        vpk[vt][mt][1] = pk2(acc[2], acc[3]);  // tokens quad*4+2,3
      }
    }
  }
  __syncthreads();  // B1

  // ============================ Phase B: attention ==========================
  // wave = (head h, query-half qh). Swapped QK^T: S^T = MFMA(K, Q):
  //   lane (quad,col): query = ni*16+col, keys = mt*16+quad*4+r  (16/lane/ni).
#pragma unroll 1
  for (int s = 0; s < 2; ++s) {
    const float scale = 0.08838834764831845f;  // 1/sqrt(C=128)
    const int h = wave & 3;
    const int qh = wave >> 2;
    const float* mbase = mask + (size_t)(b & 1023) * 4096;
    const float* bL = (s == 0 ? biasT1 : biasT2) + h * 4096;
    const int g0 = ((2 * quad) & 3) * 16 + col;      // src lane, j<4 group
    const int g1 = ((2 * quad + 1) & 3) * 16 + col;  // src lane, j>=4 group
    const int hi = quad >> 1;                        // selects mt 2ks / 2ks+1

    short8 kf[4];  // A-op: key on lane&15, channel on quad*8+j
#pragma unroll
    for (int mt = 0; mt < 4; ++mt)
      kf[mt] = *(const short8*)&sK[1 - s][h][mt * 16 + col][quad * 8];
    short8 qf[2];  // B-op: query on lane&15 (stride 36 -> two 8B loads)
#pragma unroll
    for (int ni = 0; ni < 2; ++ni) {
      const short4v* qp = (const short4v*)&sQ[s][h][(qh * 2 + ni) * 16 + col][0];
      short4v qa = qp[2 * quad], qb = qp[2 * quad + 1];
      qf[ni] = __builtin_shufflevector(qa, qb, 0, 1, 2, 3, 4, 5, 6, 7);
    }

    float bm[2][4][4];
#pragma unroll
    for (int ni = 0; ni < 2; ++ni)
#pragma unroll
      for (int mt = 0; mt < 4; ++mt) {
        f32x4 bb = *(const f32x4*)(bL + (size_t)(((qh * 2 + ni) * 4 + mt) * 64 + lane) * 4);
        f32x4 mm = *(const f32x4*)(mbase + ((qh * 2 + ni) * 16 + col) * 64 + mt * 16 + quad * 4);
#pragma unroll
        for (int r = 0; r < 4; ++r) bm[ni][mt][r] = bb[r] + mm[r];
      }

    float sv[2][4][4];
#pragma unroll
    for (int ni = 0; ni < 2; ++ni)
#pragma unroll
      for (int mt = 0; mt < 4; ++mt) {
        f32x4 acc = {0.f, 0.f, 0.f, 0.f};
        acc = MFMA(kf[mt], qf[ni], acc);  // S^T
#pragma unroll
        for (int r = 0; r < 4; ++r) sv[ni][mt][r] = fmaf(acc[r], scale, bm[ni][mt][r]);
      }

    __syncthreads();  // K[1-s] fully consumed block-wide -> region reusable
    if (sideA == 1 - s) {  // write held V[1-s] as V^T into dead K region
      unsigned short* vbw = &sK[1 - s][0][0][0];  // [4][32][72]
#pragma unroll
      for (int vt = 0; vt < 2; ++vt) {
        int nt = ntg + 16 + vt * 4;
        int cw = (nt & 7) * 16 + col;
        int hv = cw >> 5, dv = cw & 31;
#pragma unroll
        for (int mt = 0; mt < 4; ++mt) {
          uint2v vv; vv.x = vpk[vt][mt][0]; vv.y = vpk[vt][mt][1];
          *(uint2v*)(vbw + hv * 2304 + dv * 72 + mt * 16 + quad * 4) = vv;
        }
      }
    }
    __syncthreads();  // V^T[1-s] visible

    const unsigned short* vb = &sK[1 - s][0][0][0];
    short8 vf[2][2];  // B-op: d on lane&15, key on quad*8+j
#pragma unroll
    for (int dt = 0; dt < 2; ++dt)
#pragma unroll
      for (int ks = 0; ks < 2; ++ks)
        vf[dt][ks] = *(const short8*)(vb + h * 2304 + (dt * 16 + col) * 72 + ks * 32 + quad * 8);

    // softmax fully in registers (per query column; reduce across quads)
    uint32_t pk[2][4][2];
#pragma unroll
    for (int ni = 0; ni < 2; ++ni) {
      float mx = sv[ni][0][0];
#pragma unroll
      for (int mt = 0; mt < 4; ++mt)
#pragma unroll
        for (int r = 0; r < 4; ++r) mx = fmaxf(mx, sv[ni][mt][r]);
      mx = fmaxf(mx, __shfl_xor(mx, 16));
      mx = fmaxf(mx, __shfl_xor(mx, 32));
      float sum = 0.f;
#pragma unroll
      for (int mt = 0; mt < 4; ++mt)
#pragma unroll
        for (int r = 0; r < 4; ++r) {
          float e = __expf(sv[ni][mt][r] - mx);
          sv[ni][mt][r] = e;
          sum += e;
        }
      sum += __shfl_xor(sum, 16);
      sum += __shfl_xor(sum, 32);
      float inv = 1.0f / sum;
#pragma unroll
      for (int mt = 0; mt < 4; ++mt) {
        pk[ni][mt][0] = pk2(sv[ni][mt][0] * inv, sv[ni][mt][1] * inv);
        pk[ni][mt][1] = pk2(sv[ni][mt][2] * inv, sv[ni][mt][3] * inv);
      }
    }

    // quad-exchange: P (key on quad*4+r) -> PV A-frags (key on quad*8+j).
    // target (quad, ks, j): src lane = ((2*quad + (j>>2))&3)*16 + col,
    //                       src reg  = pk[ni][2*ks + (quad>>1)][(j&3)>>1 pair]
    short8 af[2][2];
#pragma unroll
    for (int ni = 0; ni < 2; ++ni)
#pragma unroll
      for (int ks = 0; ks < 2; ++ks) {
        union { uint32_t u[4]; short8 v8; } w;
        uint32_t alo, ahi;
        alo = (uint32_t)__shfl((int)pk[ni][2 * ks][0], g0);
        ahi = (uint32_t)__shfl((int)pk[ni][2 * ks + 1][0], g0);
        w.u[0] = hi ? ahi : alo;
        alo = (uint32_t)__shfl((int)pk[ni][2 * ks][1], g0);
        ahi = (uint32_t)__shfl((int)pk[ni][2 * ks + 1][1], g0);
        w.u[1] = hi ? ahi : alo;
        alo = (uint32_t)__shfl((int)pk[ni][2 * ks][0], g1);
        ahi = (uint32_t)__shfl((int)pk[ni][2 * ks + 1][0], g1);
        w.u[2] = hi ? ahi : alo;
        alo = (uint32_t)__shfl((int)pk[ni][2 * ks][1], g1);
        ahi = (uint32_t)__shfl((int)pk[ni][2 * ks + 1][1], g1);
        w.u[3] = hi ? ahi : alo;
        af[ni][ks] = w.v8;
      }

    // PV -> O into dead Q region of side s, layout [64][136]
    unsigned short* ob = &sQ[s][0][0][0];
#pragma unroll
    for (int ni = 0; ni < 2; ++ni)
#pragma unroll
      for (int dt = 0; dt < 2; ++dt) {
        f32x4 o = {0.f, 0.f, 0.f, 0.f};
        o = MFMA(af[ni][0], vf[dt][0], o);
        o = MFMA(af[ni][1], vf[dt][1], o);
#pragma unroll
        for (int r = 0; r < 4; ++r)
          ob[((qh * 2 + ni) * 16 + quad * 4 + r) * 136 + h * 32 + dt * 16 + col] = f2bf(o[r]);
      }
  }
  __syncthreads();  // O0/O1 visible

  // ====================== Phase C: proj + residual + LN =====================
  // wave = (side, row-strip mt): 16 rows x full 128 cols -> in-wave LayerNorm.
  {
    const int side = wave >> 2;
    const int mt = wave & 3;
    const unsigned short* sO = &sQ[side][0][0][0];  // [64][136]
    const unsigned short* wpp = side ? wp2p : wp1p;
    const float* bp = side ? bproj2 : bproj1;
    const float* gg = side ? g2 : g1;
    const float* bb = side ? be2 : be1;
    const float* res = (side ? y : x) + (size_t)b * 8192;
    float* o = out + (size_t)side * 33554432 + (size_t)b * 8192;

    short8 af[4];
#pragma unroll
    for (int ks = 0; ks < 4; ++ks)
      af[ks] = *(const short8*)&sO[(mt * 16 + col) * 136 + ks * 32 + quad * 8];

    float vals[8][4];
#pragma unroll
    for (int nt = 0; nt < 8; ++nt) {
      float bias = bp[nt * 16 + col];
      f32x4 acc = {bias, bias, bias, bias};
#pragma unroll
      for (int ks = 0; ks < 4; ++ks)
        acc = MFMA(af[ks], *(const short8*)(wpp + (size_t)((nt * 4 + ks) * 64 + lane) * 8), acc);
#pragma unroll
      for (int r = 0; r < 4; ++r)
        vals[nt][r] = acc[r] + res[(mt * 16 + quad * 4 + r) * 128 + nt * 16 + col];
    }

#pragma unroll
    for (int r = 0; r < 4; ++r) {
      float sum = 0.f;
#pragma unroll
      for (int nt = 0; nt < 8; ++nt) sum += vals[nt][r];
      sum += __shfl_xor(sum, 1, 16);
      sum += __shfl_xor(sum, 2, 16);
      sum += __shfl_xor(sum, 4, 16);
      sum += __shfl_xor(sum, 8, 16);
      float mean = sum * 0.0078125f;
      float vsum = 0.f;
#pragma unroll
      for (int nt = 0; nt < 8; ++nt) {
        float dd = vals[nt][r] - mean;
        vsum += dd * dd;
      }
      vsum += __shfl_xor(vsum, 1, 16);
      vsum += __shfl_xor(vsum, 2, 16);
      vsum += __shfl_xor(vsum, 4, 16);
      vsum += __shfl_xor(vsum, 8, 16);
      float rstd = rsqrtf(vsum * 0.0078125f + 1e-5f);
      int row = mt * 16 + quad * 4 + r;
#pragma unroll
      for (int nt = 0; nt < 8; ++nt) {
        int c = nt * 16 + col;
        o[row * 128 + c] = (vals[nt][r] - mean) * rstd * gg[c] + bb[c];
      }
    }
  }
}

// ---------------------------------------------------------------------------
extern "C" void kernel_launch(void* const* d_in, const int* in_sizes, int n_in,
                              void* d_out, int out_size, void* d_ws, size_t ws_size,
                              hipStream_t stream) {
  const float* x = (const float*)d_in[0];
  const float* y = (const float*)d_in[1];
  const float* mask = (const float*)d_in[2];
  const float* wqkv1 = (const float*)d_in[3];
  const float* bqkv1 = (const float*)d_in[4];
  const float* wqkv2 = (const float*)d_in[5];
  const float* bqkv2 = (const float*)d_in[6];
  const float* tbl1 = (const float*)d_in[7];
  const float* tbl2 = (const float*)d_in[8];
  const float* wproj1 = (const float*)d_in[9];
  const float* bproj1 = (const float*)d_in[10];
  const float* wproj2 = (const float*)d_in[11];
  const float* bproj2 = (const float*)d_in[12];
  const float* g1 = (const float*)d_in[13];
  const float* be1 = (const float*)d_in[14];
  const float* g2 = (const float*)d_in[15];
  const float* be2 = (const float*)d_in[16];
  const int* rpi = (const int*)d_in[17];

  // workspace layout (393216 B total)
  char* ws = (char*)d_ws;
  unsigned short* wq1p = (unsigned short*)(ws + 0);        // 98304
  unsigned short* wq2p = (unsigned short*)(ws + 98304);    // 98304
  unsigned short* wp1p = (unsigned short*)(ws + 196608);   // 32768
  unsigned short* wp2p = (unsigned short*)(ws + 229376);   // 32768
  float* bias1 = (float*)(ws + 262144);                    // 65536
  float* bias2 = (float*)(ws + 327680);                    // 65536

  prep_kernel<<<dim3(192), dim3(256), 0, stream>>>(
      wqkv1, wqkv2, wproj1, wproj2, tbl1, tbl2, rpi,
      wq1p, wq2p, wp1p, wp2p, bias1, bias2);

  wca_kernel<<<dim3(4096), dim3(512), 0, stream>>>(
      x, y, mask, bqkv1, bqkv2, bproj1, bproj2,
      g1, be1, g2, be2, wq1p, wq2p, wp1p, wp2p, bias1, bias2,
      (float*)d_out);
}

// Round 2
// 840.891 us; speedup vs baseline: 1.0463x; 1.0463x over previous
//
#include <hip/hip_runtime.h>
#include <stdint.h>

// ============================================================================
// WindowCrossAttention on MI355X (gfx950) — v3: 2 blocks/CU, spill-free.
//   B=4096 windows, N=64 tokens, C=128, H=4 heads, HD=32, NW=1024 mask groups.
//   One block (512 thr = 8 waves) per window; fully fused.
//   v2 -> v3: v2 achieved 2 blocks/CU but spilled ~77 dwords/thread to
//   scratch (WRITE_SIZE 262->909 MB). v3 restructures for <=128 live regs:
//     * Phase A loops over row-halves: afrag[2][4] (32 VGPR) resident,
//       weight B-frags re-read per half (L2-hot, cheap).
//     * vpk held as two statically-indexed arrays (vpkA/vpkB) - no dynamic
//       register indexing (would go to scratch).
//     * Phase B defers bias+mask add until after the QK^T MFMAs, so
//       bm (32 regs) never coexists with kf/qf.
//   LDS 77824 B: sQ[2][4][64][36] (O aliases), sK[2][4][64][40] (V^T aliases).
//   bf16 MFMA 16x16x32 (A: m=lane&15,k=quad*8+j; C: n=lane&15, m=quad*4+r).
// ============================================================================

typedef __attribute__((ext_vector_type(8))) short short8;   // 8 bf16
typedef __attribute__((ext_vector_type(4))) short short4v;  // 4 bf16 (8B)
typedef __attribute__((ext_vector_type(4))) float f32x4;    // MFMA C/D frag
typedef __attribute__((ext_vector_type(2))) unsigned int uint2v;

#define MFMA(a, b, c) __builtin_amdgcn_mfma_f32_16x16x32_bf16((a), (b), (c), 0, 0, 0)

static __device__ __forceinline__ unsigned short f2bf(float f) {
  union { float f; uint32_t u; } v; v.f = f;
  uint32_t u = v.u + (0x7fffu + ((v.u >> 16) & 1u));  // RNE, no NaN in data
  return (unsigned short)(u >> 16);
}
static __device__ __forceinline__ uint32_t pk2(float a, float b) {
  return (uint32_t)f2bf(a) | ((uint32_t)f2bf(b) << 16);
}

// ---------------------------------------------------------------------------
// Prep: pack weights to bf16 fragment-major (B-operand of 16x16x32 tiles);
// gather bias tables into the S^T register layout:
//   biasL[h][ni][mt][lane][r] = tbl[rpi[i*64+j]][h],
//   i = ni*16 + (lane&15)  (query), j = mt*16 + (lane>>4)*4 + r  (key).
// ---------------------------------------------------------------------------
__global__ __launch_bounds__(256) void prep_kernel(
    const float* __restrict__ wqkv1, const float* __restrict__ wqkv2,
    const float* __restrict__ wproj1, const float* __restrict__ wproj2,
    const float* __restrict__ tbl1, const float* __restrict__ tbl2,
    const int* __restrict__ rpi,
    unsigned short* __restrict__ wq1p, unsigned short* __restrict__ wq2p,
    unsigned short* __restrict__ wp1p, unsigned short* __restrict__ wp2p,
    float* __restrict__ bias1, float* __restrict__ bias2) {
  int tid = blockIdx.x * 256 + threadIdx.x;
  if (tid < 12288) {  // wqkv1 / wqkv2: K=128 (kt 0..3), N=384 (nt 0..23)
    const float* W = (tid < 6144) ? wqkv1 : wqkv2;
    unsigned short* P = (tid < 6144) ? wq1p : wq2p;
    int local = (tid < 6144) ? tid : tid - 6144;
    int tile = local >> 6, lane = local & 63;
    int nt = tile >> 2, kt = tile & 3;
    int n = nt * 16 + (lane & 15);
    int kb = kt * 32 + (lane >> 4) * 8;
    unsigned short* dst = P + (size_t)(tile * 64 + lane) * 8;
#pragma unroll
    for (int j = 0; j < 8; ++j) dst[j] = f2bf(W[(kb + j) * 384 + n]);
  } else if (tid < 16384) {  // wproj1 / wproj2
    int local = tid - 12288;
    const float* W = (local < 2048) ? wproj1 : wproj2;
    unsigned short* P = (local < 2048) ? wp1p : wp2p;
    local &= 2047;
    int tile = local >> 6, lane = local & 63;
    int nt = tile >> 2, kt = tile & 3;
    int n = nt * 16 + (lane & 15);
    int kb = kt * 32 + (lane >> 4) * 8;
    unsigned short* dst = P + (size_t)(tile * 64 + lane) * 8;
#pragma unroll
    for (int j = 0; j < 8; ++j) dst[j] = f2bf(W[(kb + j) * 128 + n]);
  } else if (tid < 49152) {  // bias gather into register layout
    int local = tid - 16384;
    const float* T = (local < 16384) ? tbl1 : tbl2;
    float* D = (local < 16384) ? bias1 : bias2;
    local &= 16383;  // h(4) ni(4) mt(4) lane(64) r(4)
    int r = local & 3;
    int ln = (local >> 2) & 63;
    int mt = (local >> 8) & 3;
    int ni = (local >> 10) & 3;
    int h = local >> 12;
    int i = ni * 16 + (ln & 15);
    int j = mt * 16 + (ln >> 4) * 4 + r;
    D[local] = T[rpi[i * 64 + j] * 4 + h];
  }
}

// ---------------------------------------------------------------------------
// Main fused kernel. LDS (77824 B total -> 2 blocks/CU):
//   sQ[2][4][64][36] bf16 : Q per side/head (token, hd), stride 36
//                           -> later aliased per side as O [64][136].
//   sK[2][4][64][40] bf16 : K per side/head, stride 40
//                           -> later aliased per side as V^T [4][32][72].
// ---------------------------------------------------------------------------
__global__ __launch_bounds__(512, 4) void wca_kernel(
    const float* __restrict__ x, const float* __restrict__ y,
    const float* __restrict__ mask,
    const float* __restrict__ bqkv1, const float* __restrict__ bqkv2,
    const float* __restrict__ bproj1, const float* __restrict__ bproj2,
    const float* __restrict__ g1, const float* __restrict__ be1,
    const float* __restrict__ g2, const float* __restrict__ be2,
    const unsigned short* __restrict__ wq1p, const unsigned short* __restrict__ wq2p,
    const unsigned short* __restrict__ wp1p, const unsigned short* __restrict__ wp2p,
    const float* __restrict__ biasT1, const float* __restrict__ biasT2,
    float* __restrict__ out) {
  __shared__ __align__(16) unsigned short sQ[2][4][64][36];
  __shared__ __align__(16) unsigned short sK[2][4][64][40];

  const int b = blockIdx.x;
  const int tid = (int)threadIdx.x;
  const int wave = tid >> 6;
  const int lane = tid & 63;
  const int quad = lane >> 4;
  const int col = lane & 15;
  const int sideA = wave >> 2;  // phase-A identity
  const int ntg = wave & 3;

  // V tiles held in regs (bf16 packed), statically indexed:
  //   vpkA = rows mt 0..1, vpkB = rows mt 2..3; [vt][mi][pair]
  uint32_t vpkA[2][2][2], vpkB[2][2][2];

  // ============================ Phase A: QKV GEMM ===========================
  // wave = (sideA, ntg); tiles nt = ntg + 4t: t0,1 -> Q; t2,3 -> K; V last.
  // Row-half loop keeps only 2 A-tiles (32 VGPR) resident; B-frags re-read
  // per half from the L2-hot weight pack.
  {
    const float* src = (sideA ? y : x) + (size_t)b * 8192;
    const unsigned short* wp = sideA ? wq2p : wq1p;
    const float* bq = sideA ? bqkv2 : bqkv1;

#pragma unroll 1
    for (int mh = 0; mh < 2; ++mh) {
      short8 afrag[2][4];
#pragma unroll
      for (int mi = 0; mi < 2; ++mi) {
        int m = (mh * 2 + mi) * 16 + col;
#pragma unroll
        for (int ks = 0; ks < 4; ++ks) {
          const float* p = src + m * 128 + ks * 32 + quad * 8;
          float4 lo = *(const float4*)(p);
          float4 hi4 = *(const float4*)(p + 4);
          short8 f;
          f[0] = (short)f2bf(lo.x); f[1] = (short)f2bf(lo.y);
          f[2] = (short)f2bf(lo.z); f[3] = (short)f2bf(lo.w);
          f[4] = (short)f2bf(hi4.x); f[5] = (short)f2bf(hi4.y);
          f[6] = (short)f2bf(hi4.z); f[7] = (short)f2bf(hi4.w);
          afrag[mi][ks] = f;
        }
      }

#pragma unroll 1
      for (int t = 0; t < 4; ++t) {  // Q (t<2) then K (t>=2) tiles
        int nt = ntg + t * 4;
        float bias = bq[nt * 16 + col];
        short8 bfrag[4];
#pragma unroll
        for (int ks = 0; ks < 4; ++ks)
          bfrag[ks] = *(const short8*)(wp + (size_t)((nt * 4 + ks) * 64 + lane) * 8);
        int cw = (nt & 7) * 16 + col;
        int hq = cw >> 5, d = cw & 31;
#pragma unroll
        for (int mi = 0; mi < 2; ++mi) {
          f32x4 acc = {bias, bias, bias, bias};
#pragma unroll
          for (int ks = 0; ks < 4; ++ks) acc = MFMA(afrag[mi][ks], bfrag[ks], acc);
#pragma unroll
          for (int r = 0; r < 4; ++r) {
            int row = (mh * 2 + mi) * 16 + quad * 4 + r;
            unsigned short v = f2bf(acc[r]);
            if (t < 2) sQ[sideA][hq][row][d] = v;
            else       sK[sideA][hq][row][d] = v;
          }
        }
      }

#pragma unroll
      for (int vt = 0; vt < 2; ++vt) {  // V tiles -> registers (packed bf16)
        int nt = ntg + 16 + vt * 4;
        float bias = bq[nt * 16 + col];
        short8 bfrag[4];
#pragma unroll
        for (int ks = 0; ks < 4; ++ks)
          bfrag[ks] = *(const short8*)(wp + (size_t)((nt * 4 + ks) * 64 + lane) * 8);
#pragma unroll
        for (int mi = 0; mi < 2; ++mi) {
          f32x4 acc = {bias, bias, bias, bias};
#pragma unroll
          for (int ks = 0; ks < 4; ++ks) acc = MFMA(afrag[mi][ks], bfrag[ks], acc);
          if (mh == 0) {  // wave-uniform branch -> static register indices
            vpkA[vt][mi][0] = pk2(acc[0], acc[1]);
            vpkA[vt][mi][1] = pk2(acc[2], acc[3]);
          } else {
            vpkB[vt][mi][0] = pk2(acc[0], acc[1]);
            vpkB[vt][mi][1] = pk2(acc[2], acc[3]);
          }
        }
      }
    }
  }
  __syncthreads();  // B1

  // ============================ Phase B: attention ==========================
  // wave = (head h, query-half qh). Swapped QK^T: S^T = MFMA(K, Q):
  //   lane (quad,col): query = ni*16+col, keys = mt*16+quad*4+r  (16/lane/ni).
  {
    const float scale = 0.08838834764831845f;  // 1/sqrt(C=128)
    const int h = wave & 3;
    const int qh = wave >> 2;
    const float* mbase = mask + (size_t)(b & 1023) * 4096;
    const int g0 = ((2 * quad) & 3) * 16 + col;      // shuffle src, j<4 group
    const int g1 = ((2 * quad + 1) & 3) * 16 + col;  // shuffle src, j>=4 group
    const int hi = quad >> 1;                        // selects mt 2ks / 2ks+1

#pragma unroll 1
    for (int s = 0; s < 2; ++s) {
      const float* bL = (s == 0 ? biasT1 : biasT2) + h * 4096;

      // ---- QK^T (kf/qf transient) ----
      f32x4 sv[2][4];
      {
        short8 kf[4];  // A-op: key on lane&15, channel on quad*8+j
#pragma unroll
        for (int mt = 0; mt < 4; ++mt)
          kf[mt] = *(const short8*)&sK[1 - s][h][mt * 16 + col][quad * 8];
        short8 qf[2];  // B-op: query on lane&15 (stride 36 -> two 8B loads)
#pragma unroll
        for (int ni = 0; ni < 2; ++ni) {
          const short4v* qp = (const short4v*)&sQ[s][h][(qh * 2 + ni) * 16 + col][0];
          short4v qa = qp[2 * quad], qb = qp[2 * quad + 1];
          qf[ni] = __builtin_shufflevector(qa, qb, 0, 1, 2, 3, 4, 5, 6, 7);
        }
#pragma unroll
        for (int ni = 0; ni < 2; ++ni)
#pragma unroll
          for (int mt = 0; mt < 4; ++mt) {
            f32x4 z = {0.f, 0.f, 0.f, 0.f};
            sv[ni][mt] = MFMA(kf[mt], qf[ni], z);
          }
      }

      // ---- scale + bias + mask (transient 8-reg loads) ----
#pragma unroll
      for (int ni = 0; ni < 2; ++ni)
#pragma unroll
        for (int mt = 0; mt < 4; ++mt) {
          f32x4 bb = *(const f32x4*)(bL + (size_t)(((qh * 2 + ni) * 4 + mt) * 64 + lane) * 4);
          f32x4 mm = *(const f32x4*)(mbase + ((qh * 2 + ni) * 16 + col) * 64 + mt * 16 + quad * 4);
#pragma unroll
          for (int r = 0; r < 4; ++r)
            sv[ni][mt][r] = fmaf(sv[ni][mt][r], scale, bb[r] + mm[r]);
        }

      __syncthreads();  // K[1-s] fully consumed block-wide -> region reusable
      if (sideA == 1 - s) {  // write held V[1-s] as V^T into dead K region
        unsigned short* vbw = &sK[1 - s][0][0][0];  // [4][32][72]
#pragma unroll
        for (int vt = 0; vt < 2; ++vt) {
          int nt = ntg + 16 + vt * 4;
          int cw = (nt & 7) * 16 + col;
          int hv = cw >> 5, dv = cw & 31;
#pragma unroll
          for (int mt = 0; mt < 4; ++mt) {
            uint2v vv;
            if (mt < 2) { vv.x = vpkA[vt][mt][0];     vv.y = vpkA[vt][mt][1]; }
            else        { vv.x = vpkB[vt][mt - 2][0]; vv.y = vpkB[vt][mt - 2][1]; }
            *(uint2v*)(vbw + hv * 2304 + dv * 72 + mt * 16 + quad * 4) = vv;
          }
        }
      }
      __syncthreads();  // V^T[1-s] visible

      // ---- softmax fully in registers (per query column) ----
      uint32_t pk[2][4][2];
#pragma unroll
      for (int ni = 0; ni < 2; ++ni) {
        float mx = sv[ni][0][0];
#pragma unroll
        for (int mt = 0; mt < 4; ++mt)
#pragma unroll
          for (int r = 0; r < 4; ++r) mx = fmaxf(mx, sv[ni][mt][r]);
        mx = fmaxf(mx, __shfl_xor(mx, 16));
        mx = fmaxf(mx, __shfl_xor(mx, 32));
        float sum = 0.f;
#pragma unroll
        for (int mt = 0; mt < 4; ++mt)
#pragma unroll
          for (int r = 0; r < 4; ++r) {
            float e = __expf(sv[ni][mt][r] - mx);
            sv[ni][mt][r] = e;
            sum += e;
          }
        sum += __shfl_xor(sum, 16);
        sum += __shfl_xor(sum, 32);
        float inv = 1.0f / sum;
#pragma unroll
        for (int mt = 0; mt < 4; ++mt) {
          pk[ni][mt][0] = pk2(sv[ni][mt][0] * inv, sv[ni][mt][1] * inv);
          pk[ni][mt][1] = pk2(sv[ni][mt][2] * inv, sv[ni][mt][3] * inv);
        }
      }

      // ---- V fragments ----
      const unsigned short* vb = &sK[1 - s][0][0][0];
      short8 vf[2][2];  // B-op: d on lane&15, key on quad*8+j
#pragma unroll
      for (int dt = 0; dt < 2; ++dt)
#pragma unroll
        for (int ks = 0; ks < 2; ++ks)
          vf[dt][ks] = *(const short8*)(vb + h * 2304 + (dt * 16 + col) * 72 + ks * 32 + quad * 8);

      // ---- quad-exchange: P (key on quad*4+r) -> PV A-frags (key on quad*8+j)
      short8 af[2][2];
#pragma unroll
      for (int ni = 0; ni < 2; ++ni)
#pragma unroll
        for (int ks = 0; ks < 2; ++ks) {
          union { uint32_t u[4]; short8 v8; } w;
          uint32_t alo, ahi;
          alo = (uint32_t)__shfl((int)pk[ni][2 * ks][0], g0);
          ahi = (uint32_t)__shfl((int)pk[ni][2 * ks + 1][0], g0);
          w.u[0] = hi ? ahi : alo;
          alo = (uint32_t)__shfl((int)pk[ni][2 * ks][1], g0);
          ahi = (uint32_t)__shfl((int)pk[ni][2 * ks + 1][1], g0);
          w.u[1] = hi ? ahi : alo;
          alo = (uint32_t)__shfl((int)pk[ni][2 * ks][0], g1);
          ahi = (uint32_t)__shfl((int)pk[ni][2 * ks + 1][0], g1);
          w.u[2] = hi ? ahi : alo;
          alo = (uint32_t)__shfl((int)pk[ni][2 * ks][1], g1);
          ahi = (uint32_t)__shfl((int)pk[ni][2 * ks + 1][1], g1);
          w.u[3] = hi ? ahi : alo;
          af[ni][ks] = w.v8;
        }

      // ---- PV -> O into dead Q region of side s, layout [64][136] ----
      unsigned short* ob = &sQ[s][0][0][0];
#pragma unroll
      for (int ni = 0; ni < 2; ++ni)
#pragma unroll
        for (int dt = 0; dt < 2; ++dt) {
          f32x4 o = {0.f, 0.f, 0.f, 0.f};
          o = MFMA(af[ni][0], vf[dt][0], o);
          o = MFMA(af[ni][1], vf[dt][1], o);
#pragma unroll
          for (int r = 0; r < 4; ++r)
            ob[((qh * 2 + ni) * 16 + quad * 4 + r) * 136 + h * 32 + dt * 16 + col] = f2bf(o[r]);
        }
    }
  }
  __syncthreads();  // O0/O1 visible

  // ====================== Phase C: proj + residual + LN =====================
  // wave = (side, row-strip mt): 16 rows x full 128 cols -> in-wave LayerNorm.
  {
    const int side = wave >> 2;
    const int mt = wave & 3;
    const unsigned short* sO = &sQ[side][0][0][0];  // [64][136]
    const unsigned short* wpp = side ? wp2p : wp1p;
    const float* bp = side ? bproj2 : bproj1;
    const float* gg = side ? g2 : g1;
    const float* bb = side ? be2 : be1;
    const float* res = (side ? y : x) + (size_t)b * 8192;
    float* o = out + (size_t)side * 33554432 + (size_t)b * 8192;

    short8 af[4];
#pragma unroll
    for (int ks = 0; ks < 4; ++ks)
      af[ks] = *(const short8*)&sO[(mt * 16 + col) * 136 + ks * 32 + quad * 8];

    float vals[8][4];
#pragma unroll
    for (int nt = 0; nt < 8; ++nt) {
      float bias = bp[nt * 16 + col];
      f32x4 acc = {bias, bias, bias, bias};
#pragma unroll
      for (int ks = 0; ks < 4; ++ks)
        acc = MFMA(af[ks], *(const short8*)(wpp + (size_t)((nt * 4 + ks) * 64 + lane) * 8), acc);
#pragma unroll
      for (int r = 0; r < 4; ++r)
        vals[nt][r] = acc[r] + res[(mt * 16 + quad * 4 + r) * 128 + nt * 16 + col];
    }

#pragma unroll
    for (int r = 0; r < 4; ++r) {
      float sum = 0.f;
#pragma unroll
      for (int nt = 0; nt < 8; ++nt) sum += vals[nt][r];
      sum += __shfl_xor(sum, 1, 16);
      sum += __shfl_xor(sum, 2, 16);
      sum += __shfl_xor(sum, 4, 16);
      sum += __shfl_xor(sum, 8, 16);
      float mean = sum * 0.0078125f;
      float vsum = 0.f;
#pragma unroll
      for (int nt = 0; nt < 8; ++nt) {
        float dd = vals[nt][r] - mean;
        vsum += dd * dd;
      }
      vsum += __shfl_xor(vsum, 1, 16);
      vsum += __shfl_xor(vsum, 2, 16);
      vsum += __shfl_xor(vsum, 4, 16);
      vsum += __shfl_xor(vsum, 8, 16);
      float rstd = rsqrtf(vsum * 0.0078125f + 1e-5f);
      int row = mt * 16 + quad * 4 + r;
#pragma unroll
      for (int nt = 0; nt < 8; ++nt) {
        int c = nt * 16 + col;
        o[row * 128 + c] = (vals[nt][r] - mean) * rstd * gg[c] + bb[c];
      }
    }
  }
}

// ---------------------------------------------------------------------------
extern "C" void kernel_launch(void* const* d_in, const int* in_sizes, int n_in,
                              void* d_out, int out_size, void* d_ws, size_t ws_size,
                              hipStream_t stream) {
  const float* x = (const float*)d_in[0];
  const float* y = (const float*)d_in[1];
  const float* mask = (const float*)d_in[2];
  const float* wqkv1 = (const float*)d_in[3];
  const float* bqkv1 = (const float*)d_in[4];
  const float* wqkv2 = (const float*)d_in[5];
  const float* bqkv2 = (const float*)d_in[6];
  const float* tbl1 = (const float*)d_in[7];
  const float* tbl2 = (const float*)d_in[8];
  const float* wproj1 = (const float*)d_in[9];
  const float* bproj1 = (const float*)d_in[10];
  const float* wproj2 = (const float*)d_in[11];
  const float* bproj2 = (const float*)d_in[12];
  const float* g1 = (const float*)d_in[13];
  const float* be1 = (const float*)d_in[14];
  const float* g2 = (const float*)d_in[15];
  const float* be2 = (const float*)d_in[16];
  const int* rpi = (const int*)d_in[17];

  // workspace layout (393216 B total)
  char* ws = (char*)d_ws;
  unsigned short* wq1p = (unsigned short*)(ws + 0);        // 98304
  unsigned short* wq2p = (unsigned short*)(ws + 98304);    // 98304
  unsigned short* wp1p = (unsigned short*)(ws + 196608);   // 32768
  unsigned short* wp2p = (unsigned short*)(ws + 229376);   // 32768
  float* bias1 = (float*)(ws + 262144);                    // 65536
  float* bias2 = (float*)(ws + 327680);                    // 65536

  prep_kernel<<<dim3(192), dim3(256), 0, stream>>>(
      wqkv1, wqkv2, wproj1, wproj2, tbl1, tbl2, rpi,
      wq1p, wq2p, wp1p, wp2p, bias1, bias2);

  wca_kernel<<<dim3(4096), dim3(512), 0, stream>>>(
      x, y, mask, bqkv1, bqkv2, bproj1, bproj2,
      g1, be1, g2, be2, wq1p, wq2p, wp1p, wp2p, bias1, bias2,
      (float*)d_out);
}